// Round 9
// baseline (470.360 us; speedup 1.0000x reference)
//
#include <hip/hip_runtime.h>
#include <hip/hip_bf16.h>
#include <math.h>

#define DIM 192
#define NHD 6
#define HD 32
#define KSZ 7
#define HID 768
#define IMH 128
#define IMW 128
#define NPIX (IMH*IMW)
#define WIN 14
#define KPAD 40

typedef __attribute__((ext_vector_type(8))) short short8;
typedef __attribute__((ext_vector_type(4))) float f32x4;

// ---------------- fused: weight fp32->bf16 (blocks 0..1727) + LN1 (blocks 1728..) ----------------
__global__ __launch_bounds__(256) void cvt_ln1(
    const float* __restrict__ qw, const float* __restrict__ pw,
    const float* __restrict__ f1, const float* __restrict__ f2,
    __hip_bfloat16* dq, __hip_bfloat16* dp, __hip_bfloat16* df1, __hip_bfloat16* df2,
    const float* __restrict__ x, const float* __restrict__ w, const float* __restrict__ b,
    __hip_bfloat16* __restrict__ hout)
{
    int blk = blockIdx.x, t = threadIdx.x;
    if (blk < 1728) {
        const float* s; __hip_bfloat16* d; int idx;
        if (blk < 432)       { s = qw; d = dq;  idx = blk * 256 + t; }
        else if (blk < 576)  { s = pw; d = dp;  idx = (blk - 432) * 256 + t; }
        else if (blk < 1152) { s = f1; d = df1; idx = (blk - 576) * 256 + t; }
        else                 { s = f2; d = df2; idx = (blk - 1152) * 256 + t; }
        d[idx] = __float2bfloat16(s[idx]);
        return;
    }
    int wid  = ((blk - 1728) * 256 + t) >> 6;
    int lane = t & 63;
    const float* xp = x + (size_t)wid * DIM;
    float v0 = xp[lane], v1 = xp[lane + 64], v2 = xp[lane + 128];
    float s = v0 + v1 + v2;
    #pragma unroll
    for (int off = 32; off > 0; off >>= 1) s += __shfl_down(s, off);
    float mu = __shfl(s, 0) * (1.0f / DIM);
    float d0 = v0 - mu, d1 = v1 - mu, d2 = v2 - mu;
    float q = d0*d0 + d1*d1 + d2*d2;
    #pragma unroll
    for (int off = 32; off > 0; off >>= 1) q += __shfl_down(q, off);
    float rstd = rsqrtf(__shfl(q, 0) * (1.0f / DIM) + 1e-5f);
    __hip_bfloat16* op = hout + (size_t)wid * DIM;
    op[lane]       = __float2bfloat16(d0 * rstd * w[lane]       + b[lane]);
    op[lane + 64]  = __float2bfloat16(d1 * rstd * w[lane + 64]  + b[lane + 64]);
    op[lane + 128] = __float2bfloat16(d2 * rstd * w[lane + 128] + b[lane + 128]);
}

__device__ __forceinline__ void gl_lds16(const void* g, void* l) {
    __builtin_amdgcn_global_load_lds(
        (const __attribute__((address_space(1))) void*)g,
        (__attribute__((address_space(3))) void*)l, 16, 0, 0);
}

// ---------------- single-K-shot GEMM: tile 128xNT, K=192 staged whole, ONE barrier ----------------
// mode 0: qkv split -> q bf16 planar (scaled) + k/v bf16 planar   mode 1: gelu -> bf16
// NT=64: LDS 72 KB (2 blocks/CU).  NT=128: LDS 96 KB (1 block/CU, halves A re-staging).
template<int mode, int NT>
__global__ __launch_bounds__(256) void gemm_k192(
    const __hip_bfloat16* __restrict__ A, const __hip_bfloat16* __restrict__ W,
    const float* __restrict__ bias,
    __hip_bfloat16* outb, __hip_bfloat16* qb, __hip_bfloat16* kb, __hip_bfloat16* vb, int N)
{
    __shared__ __hip_bfloat16 As[128 * 192];
    __shared__ __hip_bfloat16 Bs[NT * 192];
    int tid = threadIdx.x;
    int wave = tid >> 6, lane = tid & 63;
    int m0 = blockIdx.x * 128, n0 = blockIdx.y * NT;
    int q = lane >> 4, col = lane & 15;
    const int NI = NT / 32;                 // frags per wave in N
    int wm = (wave >> 1) * 64, wn = (wave & 1) * (NI * 16);

    const __hip_bfloat16* Ab = A + (size_t)m0 * 192;
    #pragma unroll
    for (int i = 0; i < 12; i++) {
        int c = i * 256 + tid;
        int r = c / 24, kc = c - r * 24;
        int g = kc ^ (r & 7);
        gl_lds16(Ab + r * 192 + g * 8, (char*)As + (i * 256 + wave * 64) * 16);
    }
    const __hip_bfloat16* Wb = W + (size_t)n0 * 192;
    #pragma unroll
    for (int i = 0; i < NT * 24 / 256; i++) {
        int c = i * 256 + tid;
        int r = c / 24, kc = c - r * 24;
        int g = kc ^ (r & 7);
        gl_lds16(Wb + r * 192 + g * 8, (char*)Bs + (i * 256 + wave * 64) * 16);
    }
    __syncthreads();

    f32x4 acc[4][NI] = {};
    #pragma unroll
    for (int ks = 0; ks < 6; ks++) {
        short8 af[4], bf[NI];
        #pragma unroll
        for (int mi = 0; mi < 4; mi++) {
            int r = wm + mi * 16 + col;
            af[mi] = *(const short8*)&As[r * 192 + (((ks * 4 + q) ^ (r & 7)) * 8)];
        }
        #pragma unroll
        for (int ni = 0; ni < NI; ni++) {
            int r = wn + ni * 16 + col;
            bf[ni] = *(const short8*)&Bs[r * 192 + (((ks * 4 + q) ^ (r & 7)) * 8)];
        }
        #pragma unroll
        for (int mi = 0; mi < 4; mi++)
            #pragma unroll
            for (int ni = 0; ni < NI; ni++)
                acc[mi][ni] = __builtin_amdgcn_mfma_f32_16x16x32_bf16(
                    af[mi], bf[ni], acc[mi][ni], 0, 0, 0);
    }

    #pragma unroll
    for (int mi = 0; mi < 4; mi++) {
        #pragma unroll
        for (int r = 0; r < 4; r++) {
            int m = m0 + wm + mi * 16 + q * 4 + r;
            #pragma unroll
            for (int ni = 0; ni < NI; ni++) {
                int n = n0 + wn + ni * 16 + col;
                float v = acc[mi][ni][r] + bias[n];
                if (mode == 0) {
                    int h18 = n >> 5;
                    int sel = h18 / 6;
                    int head = h18 - sel * 6;
                    size_t idx = ((size_t)head * NPIX + m) * 32 + (n & 31);
                    if (sel == 0)      qb[idx] = __float2bfloat16(v * 0.17677669529663687f);
                    else if (sel == 1) kb[idx] = __float2bfloat16(v);
                    else               vb[idx] = __float2bfloat16(v);
                } else {
                    float u = 0.7978845608f * (v + 0.044715f * v * v * v);
                    float t = 1.f - 2.f / (__expf(2.f * u) + 1.f);
                    v = 0.5f * v * (1.f + t);
                    outb[(size_t)m * N + n] = __float2bfloat16(v);
                }
            }
        }
    }
}

// ---------------- proj + residual + |g1| + fused LN2: 64 rows x 192 cols, one barrier ----------------
__global__ __launch_bounds__(256) void proj_ln(
    const __hip_bfloat16* __restrict__ A, const __hip_bfloat16* __restrict__ W,
    const float* __restrict__ bias,
    float* outf, __hip_bfloat16* hb, const float* __restrict__ resid,
    const float* __restrict__ gamma, const int* __restrict__ quality,
    const float* __restrict__ lnw, const float* __restrict__ lnb)
{
    __shared__ __hip_bfloat16 As[64 * 192];    // 24 KB
    __shared__ __hip_bfloat16 Bs[192 * 192];   // 72 KB
    int tid = threadIdx.x;
    int wave = tid >> 6, lane = tid & 63;
    int q = lane >> 4, col = lane & 15;
    int m0 = blockIdx.x * 64;

    const __hip_bfloat16* Ab = A + (size_t)m0 * 192;
    #pragma unroll
    for (int i = 0; i < 6; i++) {
        int c = i * 256 + tid;
        int r = c / 24, kc = c - r * 24;
        int g = kc ^ (r & 7);
        gl_lds16(Ab + r * 192 + g * 8, (char*)As + (i * 256 + wave * 64) * 16);
    }
    #pragma unroll
    for (int i = 0; i < 18; i++) {
        int c = i * 256 + tid;
        int r = c / 24, kc = c - r * 24;
        int g = kc ^ (r & 7);
        gl_lds16(W + r * 192 + g * 8, (char*)Bs + (i * 256 + wave * 64) * 16);
    }
    __syncthreads();

    f32x4 acc[12] = {};
    #pragma unroll
    for (int ks = 0; ks < 6; ks++) {
        int rA = wave * 16 + col;
        short8 af = *(const short8*)&As[rA * 192 + (((ks * 4 + q) ^ (rA & 7)) * 8)];
        #pragma unroll
        for (int f = 0; f < 12; f++) {
            int rB = f * 16 + col;
            short8 bf = *(const short8*)&Bs[rB * 192 + (((ks * 4 + q) ^ (rB & 7)) * 8)];
            acc[f] = __builtin_amdgcn_mfma_f32_16x16x32_bf16(af, bf, acc[f], 0, 0, 0);
        }
    }

    int s = quality[0] - 1;
    float v[12][4];
    #pragma unroll
    for (int f = 0; f < 12; f++) {
        int n = f * 16 + col;
        float bi = bias[n];
        float g = fabsf(gamma[s * DIM + n]);
        #pragma unroll
        for (int r = 0; r < 4; r++) {
            int m = m0 + wave * 16 + q * 4 + r;
            v[f][r] = resid[(size_t)m * DIM + n] + g * (acc[f][r] + bi);
            outf[(size_t)m * DIM + n] = v[f][r];
        }
    }
    float sm[4] = {}, sq[4] = {};
    #pragma unroll
    for (int f = 0; f < 12; f++)
        #pragma unroll
        for (int r = 0; r < 4; r++) { sm[r] += v[f][r]; sq[r] += v[f][r] * v[f][r]; }
    #pragma unroll
    for (int off = 1; off <= 8; off <<= 1) {
        #pragma unroll
        for (int r = 0; r < 4; r++) {
            sm[r] += __shfl_xor(sm[r], off);
            sq[r] += __shfl_xor(sq[r], off);
        }
    }
    float mu[4], rstd[4];
    #pragma unroll
    for (int r = 0; r < 4; r++) {
        mu[r] = sm[r] * (1.0f / DIM);
        float var = sq[r] * (1.0f / DIM) - mu[r] * mu[r];
        rstd[r] = rsqrtf(var + 1e-5f);
    }
    #pragma unroll
    for (int f = 0; f < 12; f++) {
        int n = f * 16 + col;
        float lw = lnw[n], lb = lnb[n];
        #pragma unroll
        for (int r = 0; r < 4; r++) {
            int m = m0 + wave * 16 + q * 4 + r;
            hb[(size_t)m * DIM + n] = __float2bfloat16((v[f][r] - mu[r]) * rstd[r] * lw + lb);
        }
    }
}

// ---------------- FC2: tile 64x64, BK=192 (4 iters), + resid + |g2| ----------------
__global__ __launch_bounds__(256) void fc2_gemm(
    const __hip_bfloat16* __restrict__ A, const __hip_bfloat16* __restrict__ W,
    const float* __restrict__ bias,
    float* outf, const float* __restrict__ resid,
    const float* __restrict__ gamma, const int* __restrict__ quality)
{
    __shared__ __hip_bfloat16 As[64 * 192];   // 24 KB
    __shared__ __hip_bfloat16 Bs[64 * 192];   // 24 KB
    int tid = threadIdx.x;
    int wave = tid >> 6, lane = tid & 63;
    int q = lane >> 4, col = lane & 15;
    int m0 = blockIdx.x * 64, n0 = blockIdx.y * 64;
    int wm = (wave >> 1) * 32, wn = (wave & 1) * 32;

    f32x4 acc[2][2] = {};
    for (int k0 = 0; k0 < HID; k0 += 192) {
        #pragma unroll
        for (int i = 0; i < 6; i++) {
            int c = i * 256 + tid;
            int r = c / 24, kc = c - r * 24;
            int g = kc ^ (r & 7);
            gl_lds16(A + (size_t)(m0 + r) * HID + k0 + g * 8,
                     (char*)As + (i * 256 + wave * 64) * 16);
        }
        #pragma unroll
        for (int i = 0; i < 6; i++) {
            int c = i * 256 + tid;
            int r = c / 24, kc = c - r * 24;
            int g = kc ^ (r & 7);
            gl_lds16(W + (size_t)(n0 + r) * HID + k0 + g * 8,
                     (char*)Bs + (i * 256 + wave * 64) * 16);
        }
        __syncthreads();
        #pragma unroll
        for (int ks = 0; ks < 6; ks++) {
            short8 af[2], bf[2];
            #pragma unroll
            for (int mi = 0; mi < 2; mi++) {
                int r = wm + mi * 16 + col;
                af[mi] = *(const short8*)&As[r * 192 + (((ks * 4 + q) ^ (r & 7)) * 8)];
            }
            #pragma unroll
            for (int ni = 0; ni < 2; ni++) {
                int r = wn + ni * 16 + col;
                bf[ni] = *(const short8*)&Bs[r * 192 + (((ks * 4 + q) ^ (r & 7)) * 8)];
            }
            #pragma unroll
            for (int mi = 0; mi < 2; mi++)
                #pragma unroll
                for (int ni = 0; ni < 2; ni++)
                    acc[mi][ni] = __builtin_amdgcn_mfma_f32_16x16x32_bf16(
                        af[mi], bf[ni], acc[mi][ni], 0, 0, 0);
        }
        __syncthreads();
    }

    int s = quality[0] - 1;
    #pragma unroll
    for (int mi = 0; mi < 2; mi++) {
        #pragma unroll
        for (int r = 0; r < 4; r++) {
            int m = m0 + wm + mi * 16 + q * 4 + r;
            #pragma unroll
            for (int ni = 0; ni < 2; ni++) {
                int n = n0 + wn + ni * 16 + col;
                float g = fabsf(gamma[s * DIM + n]);
                outf[(size_t)m * DIM + n] =
                    resid[(size_t)m * DIM + n] + g * (acc[mi][ni][r] + bias[n]);
            }
        }
    }
}

// ---------------- Neighborhood attention: bf16 q/K/V, row-batched online softmax ----------------
__device__ __forceinline__ void unpack8(const __hip_bfloat16* ptr, float* f) {
    short8 s8 = *(const short8*)ptr;
    union { short8 v; unsigned u[4]; } c; c.v = s8;
    #pragma unroll
    for (int w = 0; w < 4; w++) {
        f[2*w]   = __uint_as_float(c.u[w] << 16);
        f[2*w+1] = __uint_as_float(c.u[w] & 0xffff0000u);
    }
}

__global__ __launch_bounds__(256, 4) void attn_kernel3(
    const __hip_bfloat16* __restrict__ qbuf, const __hip_bfloat16* __restrict__ kbuf,
    const __hip_bfloat16* __restrict__ vbuf, const float* __restrict__ rpb,
    __hip_bfloat16* __restrict__ out)
{
    __shared__ __hip_bfloat16 Ks[WIN * WIN * KPAD];
    __shared__ __hip_bfloat16 Vs[WIN * WIN * KPAD];
    __shared__ float rpbs[169];

    int head = blockIdx.y;
    int tile = blockIdx.x;
    int ti0 = (tile >> 4) * 8;
    int tj0 = (tile & 15) * 8;
    int wi0 = ti0 - 3; wi0 = wi0 < 0 ? 0 : (wi0 > IMH - WIN ? IMH - WIN : wi0);
    int wj0 = tj0 - 3; wj0 = wj0 < 0 ? 0 : (wj0 > IMW - WIN ? IMW - WIN : wj0);

    int tid = threadIdx.x;
    const size_t hbase = (size_t)head * NPIX;

    for (int c = tid; c < 784; c += 256) {
        int i = c / 56, part = c - i * 56;
        int n = i * WIN + (part >> 2);
        int dp = part & 3;
        size_t goff = (hbase + (size_t)(wi0 + i) * IMW + wj0) * 32 + part * 8;
        short8 kk = *(const short8*)(kbuf + goff);
        short8 vv = *(const short8*)(vbuf + goff);
        *(short8*)&Ks[n * KPAD + dp * 8] = kk;
        *(short8*)&Vs[n * KPAD + dp * 8] = vv;
    }
    if (tid < 169) rpbs[tid] = rpb[head * 169 + tid];

    int p   = tid >> 2;
    int sub = tid & 3;
    int pi = ti0 + (p >> 3), pj = tj0 + (p & 7);
    int si = pi - 3; si = si < 0 ? 0 : (si > IMH - KSZ ? IMH - KSZ : si);
    int sj = pj - 3; sj = sj < 0 ? 0 : (sj > IMW - KSZ ? IMW - KSZ : sj);
    int bi = si - wi0, bj = sj - wj0;

    // q: bf16, pre-scaled, planar [head][pix][32]
    float q[8];
    unpack8(qbuf + (hbase + (size_t)(pi * IMW + pj)) * 32 + sub * 8, q);

    __syncthreads();

    float m = -1e30f, l = 0.f;
    float acc[8] = {};
    #pragma unroll
    for (int ki = 0; ki < KSZ; ki++) {
        int rbase = (bi + ki) * WIN + bj;
        const float* rb = &rpbs[(si + ki - pi + 6) * 13 + (sj - pj + 6)];
        float s7[KSZ];
        #pragma unroll
        for (int kj = 0; kj < KSZ; kj++) {
            float kf[8];
            unpack8(&Ks[(rbase + kj) * KPAD + sub * 8], kf);
            float d = q[0]*kf[0] + q[1]*kf[1] + q[2]*kf[2] + q[3]*kf[3]
                    + q[4]*kf[4] + q[5]*kf[5] + q[6]*kf[6] + q[7]*kf[7];
            d += __shfl_xor(d, 1);
            d += __shfl_xor(d, 2);
            s7[kj] = d + rb[kj];
        }
        float rmax = s7[0];
        #pragma unroll
        for (int kj = 1; kj < KSZ; kj++) rmax = fmaxf(rmax, s7[kj]);
        float mn = fmaxf(m, rmax);
        float co = __expf(m - mn);
        l *= co;
        #pragma unroll
        for (int e = 0; e < 8; e++) acc[e] *= co;
        #pragma unroll
        for (int kj = 0; kj < KSZ; kj++) {
            float pw = __expf(s7[kj] - mn);
            l += pw;
            float vf[8];
            unpack8(&Vs[(rbase + kj) * KPAD + sub * 8], vf);
            #pragma unroll
            for (int e = 0; e < 8; e++) acc[e] += pw * vf[e];
        }
        m = mn;
    }
    float rl = 1.f / l;
    __hip_bfloat16* op = out + (size_t)(pi * IMW + pj) * DIM + head * HD + sub * 8;
    #pragma unroll
    for (int e = 0; e < 8; e++) op[e] = __float2bfloat16(acc[e] * rl);
}

extern "C" void kernel_launch(void* const* d_in, const int* in_sizes, int n_in,
                              void* d_out, int out_size, void* d_ws, size_t ws_size,
                              hipStream_t stream)
{
    const float* x      = (const float*)d_in[0];
    const float* qkv_w  = (const float*)d_in[1];
    const float* qkv_b  = (const float*)d_in[2];
    const float* proj_w = (const float*)d_in[3];
    const float* proj_b = (const float*)d_in[4];
    const float* rpb    = (const float*)d_in[5];
    const float* ln1_w  = (const float*)d_in[6];
    const float* ln1_b  = (const float*)d_in[7];
    const float* ln2_w  = (const float*)d_in[8];
    const float* ln2_b  = (const float*)d_in[9];
    const float* fc1_w  = (const float*)d_in[10];
    const float* fc1_b  = (const float*)d_in[11];
    const float* fc2_w  = (const float*)d_in[12];
    const float* fc2_b  = (const float*)d_in[13];
    const float* gamma1 = (const float*)d_in[14];
    const float* gamma2 = (const float*)d_in[15];
    const int*   quality= (const int*)d_in[16];
    float* out = (float*)d_out;

    char* ws = (char*)d_ws;
    __hip_bfloat16* qbuf   = (__hip_bfloat16*)ws;                // 6.29MB bf16 planar
    __hip_bfloat16* kbuf   = (__hip_bfloat16*)(ws + 6291456);    // 6.29MB
    __hip_bfloat16* vbuf   = (__hip_bfloat16*)(ws + 12582912);   // 6.29MB
    __hip_bfloat16* m1     = (__hip_bfloat16*)ws;                // 25.2MB, aliases q/k/v after attn
    __hip_bfloat16* h      = (__hip_bfloat16*)(ws + 37748736);
    __hip_bfloat16* attn_b = (__hip_bfloat16*)(ws + 44040192);
    __hip_bfloat16* wq     = (__hip_bfloat16*)(ws + 50331648);
    __hip_bfloat16* wp     = (__hip_bfloat16*)(ws + 50552832);
    __hip_bfloat16* wf1    = (__hip_bfloat16*)(ws + 50626560);
    __hip_bfloat16* wf2    = (__hip_bfloat16*)(ws + 50921472);

    // 0. weights->bf16 + LN1 fused
    cvt_ln1<<<1728 + NPIX / 4, 256, 0, stream>>>(
        qkv_w, proj_w, fc1_w, fc2_w, wq, wp, wf1, wf2, x, ln1_w, ln1_b, h);
    // 1. QKV GEMM (single-K-shot 128x64) -> q/k/v bf16 planar (q pre-scaled)
    gemm_k192<0, 64><<<dim3(NPIX / 128, 9), 256, 0, stream>>>(
        h, wq, qkv_b, nullptr, qbuf, kbuf, vbuf, 576);
    // 2. neighborhood attention -> attn_b (bf16)
    attn_kernel3<<<dim3(256, NHD), 256, 0, stream>>>(qbuf, kbuf, vbuf, rpb, attn_b);
    // 3. proj + residual + LN2 (fused, single-shot): out = x + |g1|*(attn@wp^T+b), h = LN2(out)
    proj_ln<<<NPIX / 64, 256, 0, stream>>>(
        attn_b, wp, proj_b, out, h, x, gamma1, quality, ln2_w, ln2_b);
    // 4. FC1 + GELU (single-K-shot 128x128, halved A re-staging) -> m1 (bf16)
    gemm_k192<1, 128><<<dim3(NPIX / 128, 6), 256, 0, stream>>>(
        h, wf1, fc1_b, m1, nullptr, nullptr, nullptr, HID);
    // 5. FC2 + residual (64x64, BK=192): out += |g2|*(m1@wf2^T+b)
    fc2_gemm<<<dim3(NPIX / 64, 3), 256, 0, stream>>>(
        m1, wf2, fc2_b, out, out, gamma2, quality);
}

// Round 10
// 183.088 us; speedup vs baseline: 2.5690x; 2.5690x over previous
//
#include <hip/hip_runtime.h>
#include <hip/hip_bf16.h>
#include <math.h>

#define DIM 192
#define NHD 6
#define HD 32
#define KSZ 7
#define HID 768
#define IMH 128
#define IMW 128
#define NPIX (IMH*IMW)
#define WIN 14
#define KPAD 40

typedef __attribute__((ext_vector_type(8))) short short8;
typedef __attribute__((ext_vector_type(4))) float f32x4;

// ---------------- fused: weight fp32->bf16 (blocks 0..1727) + LN1 (blocks 1728..) ----------------
__global__ __launch_bounds__(256) void cvt_ln1(
    const float* __restrict__ qw, const float* __restrict__ pw,
    const float* __restrict__ f1, const float* __restrict__ f2,
    __hip_bfloat16* dq, __hip_bfloat16* dp, __hip_bfloat16* df1, __hip_bfloat16* df2,
    const float* __restrict__ x, const float* __restrict__ w, const float* __restrict__ b,
    __hip_bfloat16* __restrict__ hout)
{
    int blk = blockIdx.x, t = threadIdx.x;
    if (blk < 1728) {
        const float* s; __hip_bfloat16* d; int idx;
        if (blk < 432)       { s = qw; d = dq;  idx = blk * 256 + t; }
        else if (blk < 576)  { s = pw; d = dp;  idx = (blk - 432) * 256 + t; }
        else if (blk < 1152) { s = f1; d = df1; idx = (blk - 576) * 256 + t; }
        else                 { s = f2; d = df2; idx = (blk - 1152) * 256 + t; }
        d[idx] = __float2bfloat16(s[idx]);
        return;
    }
    int wid  = ((blk - 1728) * 256 + t) >> 6;
    int lane = t & 63;
    const float* xp = x + (size_t)wid * DIM;
    float v0 = xp[lane], v1 = xp[lane + 64], v2 = xp[lane + 128];
    float s = v0 + v1 + v2;
    #pragma unroll
    for (int off = 32; off > 0; off >>= 1) s += __shfl_down(s, off);
    float mu = __shfl(s, 0) * (1.0f / DIM);
    float d0 = v0 - mu, d1 = v1 - mu, d2 = v2 - mu;
    float q = d0*d0 + d1*d1 + d2*d2;
    #pragma unroll
    for (int off = 32; off > 0; off >>= 1) q += __shfl_down(q, off);
    float rstd = rsqrtf(__shfl(q, 0) * (1.0f / DIM) + 1e-5f);
    __hip_bfloat16* op = hout + (size_t)wid * DIM;
    op[lane]       = __float2bfloat16(d0 * rstd * w[lane]       + b[lane]);
    op[lane + 64]  = __float2bfloat16(d1 * rstd * w[lane + 64]  + b[lane + 64]);
    op[lane + 128] = __float2bfloat16(d2 * rstd * w[lane + 128] + b[lane + 128]);
}

__device__ __forceinline__ void gl_lds16(const void* g, void* l) {
    __builtin_amdgcn_global_load_lds(
        (const __attribute__((address_space(1))) void*)g,
        (__attribute__((address_space(3))) void*)l, 16, 0, 0);
}

// ---------------- single-K-shot GEMM: tile 128x64, K=192 staged whole, ONE barrier ----------------
// mode 0: qkv split -> q fp32 planar (scaled) + k/v bf16 planar   mode 1: gelu -> bf16
template<int mode>
__global__ __launch_bounds__(256) void gemm_k192(
    const __hip_bfloat16* __restrict__ A, const __hip_bfloat16* __restrict__ W,
    const float* __restrict__ bias,
    float* outf, __hip_bfloat16* outb, __hip_bfloat16* kb, __hip_bfloat16* vb, int N)
{
    __shared__ __hip_bfloat16 As[128 * 192];   // 48 KB
    __shared__ __hip_bfloat16 Bs[64 * 192];    // 24 KB
    int tid = threadIdx.x;
    int wave = tid >> 6, lane = tid & 63;
    int m0 = blockIdx.x * 128, n0 = blockIdx.y * 64;
    int q = lane >> 4, col = lane & 15;
    int wm = (wave >> 1) * 64, wn = (wave & 1) * 32;

    const __hip_bfloat16* Ab = A + (size_t)m0 * 192;
    #pragma unroll
    for (int i = 0; i < 12; i++) {
        int c = i * 256 + tid;
        int r = c / 24, kc = c - r * 24;
        int g = kc ^ (r & 7);
        gl_lds16(Ab + r * 192 + g * 8, (char*)As + (i * 256 + wave * 64) * 16);
    }
    const __hip_bfloat16* Wb = W + (size_t)n0 * 192;
    #pragma unroll
    for (int i = 0; i < 6; i++) {
        int c = i * 256 + tid;
        int r = c / 24, kc = c - r * 24;
        int g = kc ^ (r & 7);
        gl_lds16(Wb + r * 192 + g * 8, (char*)Bs + (i * 256 + wave * 64) * 16);
    }
    __syncthreads();

    f32x4 acc[4][2] = {};
    #pragma unroll
    for (int ks = 0; ks < 6; ks++) {
        short8 af[4], bf[2];
        #pragma unroll
        for (int mi = 0; mi < 4; mi++) {
            int r = wm + mi * 16 + col;
            af[mi] = *(const short8*)&As[r * 192 + (((ks * 4 + q) ^ (r & 7)) * 8)];
        }
        #pragma unroll
        for (int ni = 0; ni < 2; ni++) {
            int r = wn + ni * 16 + col;
            bf[ni] = *(const short8*)&Bs[r * 192 + (((ks * 4 + q) ^ (r & 7)) * 8)];
        }
        #pragma unroll
        for (int mi = 0; mi < 4; mi++)
            #pragma unroll
            for (int ni = 0; ni < 2; ni++)
                acc[mi][ni] = __builtin_amdgcn_mfma_f32_16x16x32_bf16(
                    af[mi], bf[ni], acc[mi][ni], 0, 0, 0);
    }

    #pragma unroll
    for (int mi = 0; mi < 4; mi++) {
        #pragma unroll
        for (int r = 0; r < 4; r++) {
            int m = m0 + wm + mi * 16 + q * 4 + r;
            #pragma unroll
            for (int ni = 0; ni < 2; ni++) {
                int n = n0 + wn + ni * 16 + col;
                float v = acc[mi][ni][r] + bias[n];
                if (mode == 0) {
                    int h18 = n >> 5;
                    int sel = h18 / 6;
                    int head = h18 - sel * 6;
                    size_t idx = ((size_t)head * NPIX + m) * 32 + (n & 31);
                    if (sel == 0)      outf[idx] = v * 0.17677669529663687f;
                    else if (sel == 1) kb[idx] = __float2bfloat16(v);
                    else               vb[idx] = __float2bfloat16(v);
                } else {
                    float u = 0.7978845608f * (v + 0.044715f * v * v * v);
                    float t = 1.f - 2.f / (__expf(2.f * u) + 1.f);
                    v = 0.5f * v * (1.f + t);
                    outb[(size_t)m * N + n] = __float2bfloat16(v);
                }
            }
        }
    }
}

// ---------------- proj + residual + |g1| + fused LN2: 64 rows x 192 cols, one barrier ----------------
__global__ __launch_bounds__(256) void proj_ln(
    const __hip_bfloat16* __restrict__ A, const __hip_bfloat16* __restrict__ W,
    const float* __restrict__ bias,
    float* outf, __hip_bfloat16* hb, const float* __restrict__ resid,
    const float* __restrict__ gamma, const int* __restrict__ quality,
    const float* __restrict__ lnw, const float* __restrict__ lnb)
{
    __shared__ __hip_bfloat16 As[64 * 192];    // 24 KB
    __shared__ __hip_bfloat16 Bs[192 * 192];   // 72 KB
    int tid = threadIdx.x;
    int wave = tid >> 6, lane = tid & 63;
    int q = lane >> 4, col = lane & 15;
    int m0 = blockIdx.x * 64;

    const __hip_bfloat16* Ab = A + (size_t)m0 * 192;
    #pragma unroll
    for (int i = 0; i < 6; i++) {
        int c = i * 256 + tid;
        int r = c / 24, kc = c - r * 24;
        int g = kc ^ (r & 7);
        gl_lds16(Ab + r * 192 + g * 8, (char*)As + (i * 256 + wave * 64) * 16);
    }
    #pragma unroll
    for (int i = 0; i < 18; i++) {
        int c = i * 256 + tid;
        int r = c / 24, kc = c - r * 24;
        int g = kc ^ (r & 7);
        gl_lds16(W + r * 192 + g * 8, (char*)Bs + (i * 256 + wave * 64) * 16);
    }
    __syncthreads();

    f32x4 acc[12] = {};
    #pragma unroll
    for (int ks = 0; ks < 6; ks++) {
        int rA = wave * 16 + col;
        short8 af = *(const short8*)&As[rA * 192 + (((ks * 4 + q) ^ (rA & 7)) * 8)];
        #pragma unroll
        for (int f = 0; f < 12; f++) {
            int rB = f * 16 + col;
            short8 bf = *(const short8*)&Bs[rB * 192 + (((ks * 4 + q) ^ (rB & 7)) * 8)];
            acc[f] = __builtin_amdgcn_mfma_f32_16x16x32_bf16(af, bf, acc[f], 0, 0, 0);
        }
    }

    int s = quality[0] - 1;
    float v[12][4];
    #pragma unroll
    for (int f = 0; f < 12; f++) {
        int n = f * 16 + col;
        float bi = bias[n];
        float g = fabsf(gamma[s * DIM + n]);
        #pragma unroll
        for (int r = 0; r < 4; r++) {
            int m = m0 + wave * 16 + q * 4 + r;
            v[f][r] = resid[(size_t)m * DIM + n] + g * (acc[f][r] + bi);
            outf[(size_t)m * DIM + n] = v[f][r];
        }
    }
    float sm[4] = {}, sq[4] = {};
    #pragma unroll
    for (int f = 0; f < 12; f++)
        #pragma unroll
        for (int r = 0; r < 4; r++) { sm[r] += v[f][r]; sq[r] += v[f][r] * v[f][r]; }
    #pragma unroll
    for (int off = 1; off <= 8; off <<= 1) {
        #pragma unroll
        for (int r = 0; r < 4; r++) {
            sm[r] += __shfl_xor(sm[r], off);
            sq[r] += __shfl_xor(sq[r], off);
        }
    }
    float mu[4], rstd[4];
    #pragma unroll
    for (int r = 0; r < 4; r++) {
        mu[r] = sm[r] * (1.0f / DIM);
        float var = sq[r] * (1.0f / DIM) - mu[r] * mu[r];
        rstd[r] = rsqrtf(var + 1e-5f);
    }
    #pragma unroll
    for (int f = 0; f < 12; f++) {
        int n = f * 16 + col;
        float lw = lnw[n], lb = lnb[n];
        #pragma unroll
        for (int r = 0; r < 4; r++) {
            int m = m0 + wave * 16 + q * 4 + r;
            hb[(size_t)m * DIM + n] = __float2bfloat16((v[f][r] - mu[r]) * rstd[r] * lw + lb);
        }
    }
}

// ---------------- FC2: tile 64x64, BK=192 (4 iters), + resid + |g2| ----------------
__global__ __launch_bounds__(256) void fc2_gemm(
    const __hip_bfloat16* __restrict__ A, const __hip_bfloat16* __restrict__ W,
    const float* __restrict__ bias,
    float* outf, const float* __restrict__ resid,
    const float* __restrict__ gamma, const int* __restrict__ quality)
{
    __shared__ __hip_bfloat16 As[64 * 192];   // 24 KB
    __shared__ __hip_bfloat16 Bs[64 * 192];   // 24 KB
    int tid = threadIdx.x;
    int wave = tid >> 6, lane = tid & 63;
    int q = lane >> 4, col = lane & 15;
    int m0 = blockIdx.x * 64, n0 = blockIdx.y * 64;
    int wm = (wave >> 1) * 32, wn = (wave & 1) * 32;

    f32x4 acc[2][2] = {};
    for (int k0 = 0; k0 < HID; k0 += 192) {
        #pragma unroll
        for (int i = 0; i < 6; i++) {
            int c = i * 256 + tid;
            int r = c / 24, kc = c - r * 24;
            int g = kc ^ (r & 7);
            gl_lds16(A + (size_t)(m0 + r) * HID + k0 + g * 8,
                     (char*)As + (i * 256 + wave * 64) * 16);
        }
        #pragma unroll
        for (int i = 0; i < 6; i++) {
            int c = i * 256 + tid;
            int r = c / 24, kc = c - r * 24;
            int g = kc ^ (r & 7);
            gl_lds16(W + (size_t)(n0 + r) * HID + k0 + g * 8,
                     (char*)Bs + (i * 256 + wave * 64) * 16);
        }
        __syncthreads();
        #pragma unroll
        for (int ks = 0; ks < 6; ks++) {
            short8 af[2], bf[2];
            #pragma unroll
            for (int mi = 0; mi < 2; mi++) {
                int r = wm + mi * 16 + col;
                af[mi] = *(const short8*)&As[r * 192 + (((ks * 4 + q) ^ (r & 7)) * 8)];
            }
            #pragma unroll
            for (int ni = 0; ni < 2; ni++) {
                int r = wn + ni * 16 + col;
                bf[ni] = *(const short8*)&Bs[r * 192 + (((ks * 4 + q) ^ (r & 7)) * 8)];
            }
            #pragma unroll
            for (int mi = 0; mi < 2; mi++)
                #pragma unroll
                for (int ni = 0; ni < 2; ni++)
                    acc[mi][ni] = __builtin_amdgcn_mfma_f32_16x16x32_bf16(
                        af[mi], bf[ni], acc[mi][ni], 0, 0, 0);
        }
        __syncthreads();
    }

    int s = quality[0] - 1;
    #pragma unroll
    for (int mi = 0; mi < 2; mi++) {
        #pragma unroll
        for (int r = 0; r < 4; r++) {
            int m = m0 + wm + mi * 16 + q * 4 + r;
            #pragma unroll
            for (int ni = 0; ni < 2; ni++) {
                int n = n0 + wn + ni * 16 + col;
                float g = fabsf(gamma[s * DIM + n]);
                outf[(size_t)m * DIM + n] =
                    resid[(size_t)m * DIM + n] + g * (acc[mi][ni][r] + bias[n]);
            }
        }
    }
}

// ---------------- Neighborhood attention: bf16 K/V, row-batched online softmax ----------------
__device__ __forceinline__ void unpack8(const __hip_bfloat16* ptr, float* f) {
    short8 s8 = *(const short8*)ptr;
    union { short8 v; unsigned u[4]; } c; c.v = s8;
    #pragma unroll
    for (int w = 0; w < 4; w++) {
        f[2*w]   = __uint_as_float(c.u[w] << 16);
        f[2*w+1] = __uint_as_float(c.u[w] & 0xffff0000u);
    }
}

__global__ __launch_bounds__(256, 4) void attn_kernel3(
    const float* __restrict__ qbuf, const __hip_bfloat16* __restrict__ kbuf,
    const __hip_bfloat16* __restrict__ vbuf, const float* __restrict__ rpb,
    __hip_bfloat16* __restrict__ out)
{
    __shared__ __hip_bfloat16 Ks[WIN * WIN * KPAD];
    __shared__ __hip_bfloat16 Vs[WIN * WIN * KPAD];
    __shared__ float rpbs[169];

    int head = blockIdx.y;
    int tile = blockIdx.x;
    int ti0 = (tile >> 4) * 8;
    int tj0 = (tile & 15) * 8;
    int wi0 = ti0 - 3; wi0 = wi0 < 0 ? 0 : (wi0 > IMH - WIN ? IMH - WIN : wi0);
    int wj0 = tj0 - 3; wj0 = wj0 < 0 ? 0 : (wj0 > IMW - WIN ? IMW - WIN : wj0);

    int tid = threadIdx.x;
    const size_t hbase = (size_t)head * NPIX;

    for (int c = tid; c < 784; c += 256) {
        int i = c / 56, part = c - i * 56;
        int n = i * WIN + (part >> 2);
        int dp = part & 3;
        size_t goff = (hbase + (size_t)(wi0 + i) * IMW + wj0) * 32 + part * 8;
        short8 kk = *(const short8*)(kbuf + goff);
        short8 vv = *(const short8*)(vbuf + goff);
        *(short8*)&Ks[n * KPAD + dp * 8] = kk;
        *(short8*)&Vs[n * KPAD + dp * 8] = vv;
    }
    if (tid < 169) rpbs[tid] = rpb[head * 169 + tid];

    int p   = tid >> 2;
    int sub = tid & 3;
    int pi = ti0 + (p >> 3), pj = tj0 + (p & 7);
    int si = pi - 3; si = si < 0 ? 0 : (si > IMH - KSZ ? IMH - KSZ : si);
    int sj = pj - 3; sj = sj < 0 ? 0 : (sj > IMW - KSZ ? IMW - KSZ : sj);
    int bi = si - wi0, bj = sj - wj0;

    const float4* qp = (const float4*)(qbuf + (hbase + (size_t)(pi * IMW + pj)) * 32 + sub * 8);
    float4 q0 = qp[0], q1 = qp[1];
    float q[8] = {q0.x, q0.y, q0.z, q0.w, q1.x, q1.y, q1.z, q1.w};

    __syncthreads();

    float m = -1e30f, l = 0.f;
    float acc[8] = {};
    #pragma unroll
    for (int ki = 0; ki < KSZ; ki++) {
        int rbase = (bi + ki) * WIN + bj;
        const float* rb = &rpbs[(si + ki - pi + 6) * 13 + (sj - pj + 6)];
        float s7[KSZ];
        #pragma unroll
        for (int kj = 0; kj < KSZ; kj++) {
            float kf[8];
            unpack8(&Ks[(rbase + kj) * KPAD + sub * 8], kf);
            float d = q[0]*kf[0] + q[1]*kf[1] + q[2]*kf[2] + q[3]*kf[3]
                    + q[4]*kf[4] + q[5]*kf[5] + q[6]*kf[6] + q[7]*kf[7];
            d += __shfl_xor(d, 1);
            d += __shfl_xor(d, 2);
            s7[kj] = d + rb[kj];
        }
        float rmax = s7[0];
        #pragma unroll
        for (int kj = 1; kj < KSZ; kj++) rmax = fmaxf(rmax, s7[kj]);
        float mn = fmaxf(m, rmax);
        float co = __expf(m - mn);
        l *= co;
        #pragma unroll
        for (int e = 0; e < 8; e++) acc[e] *= co;
        #pragma unroll
        for (int kj = 0; kj < KSZ; kj++) {
            float pw = __expf(s7[kj] - mn);
            l += pw;
            float vf[8];
            unpack8(&Vs[(rbase + kj) * KPAD + sub * 8], vf);
            #pragma unroll
            for (int e = 0; e < 8; e++) acc[e] += pw * vf[e];
        }
        m = mn;
    }
    float rl = 1.f / l;
    __hip_bfloat16* op = out + (size_t)(pi * IMW + pj) * DIM + head * HD + sub * 8;
    #pragma unroll
    for (int e = 0; e < 8; e++) op[e] = __float2bfloat16(acc[e] * rl);
}

extern "C" void kernel_launch(void* const* d_in, const int* in_sizes, int n_in,
                              void* d_out, int out_size, void* d_ws, size_t ws_size,
                              hipStream_t stream)
{
    const float* x      = (const float*)d_in[0];
    const float* qkv_w  = (const float*)d_in[1];
    const float* qkv_b  = (const float*)d_in[2];
    const float* proj_w = (const float*)d_in[3];
    const float* proj_b = (const float*)d_in[4];
    const float* rpb    = (const float*)d_in[5];
    const float* ln1_w  = (const float*)d_in[6];
    const float* ln1_b  = (const float*)d_in[7];
    const float* ln2_w  = (const float*)d_in[8];
    const float* ln2_b  = (const float*)d_in[9];
    const float* fc1_w  = (const float*)d_in[10];
    const float* fc1_b  = (const float*)d_in[11];
    const float* fc2_w  = (const float*)d_in[12];
    const float* fc2_b  = (const float*)d_in[13];
    const float* gamma1 = (const float*)d_in[14];
    const float* gamma2 = (const float*)d_in[15];
    const int*   quality= (const int*)d_in[16];
    float* out = (float*)d_out;

    char* ws = (char*)d_ws;
    float*          qbuf   = (float*)ws;                         // 12.58MB fp32 planar
    __hip_bfloat16* kbuf   = (__hip_bfloat16*)(ws + 12582912);   // 6.29MB
    __hip_bfloat16* vbuf   = (__hip_bfloat16*)(ws + 18874368);   // 6.29MB
    __hip_bfloat16* m1     = (__hip_bfloat16*)ws;                // aliases q/k/v after attention
    __hip_bfloat16* h      = (__hip_bfloat16*)(ws + 37748736);
    __hip_bfloat16* attn_b = (__hip_bfloat16*)(ws + 44040192);
    __hip_bfloat16* wq     = (__hip_bfloat16*)(ws + 50331648);
    __hip_bfloat16* wp     = (__hip_bfloat16*)(ws + 50552832);
    __hip_bfloat16* wf1    = (__hip_bfloat16*)(ws + 50626560);
    __hip_bfloat16* wf2    = (__hip_bfloat16*)(ws + 50921472);

    // 0. weights->bf16 + LN1 fused
    cvt_ln1<<<1728 + NPIX / 4, 256, 0, stream>>>(
        qkv_w, proj_w, fc1_w, fc2_w, wq, wp, wf1, wf2, x, ln1_w, ln1_b, h);
    // 1. QKV GEMM (single-K-shot 128x64) -> q fp32 planar (scaled) + k/v bf16 planar
    gemm_k192<0><<<dim3(NPIX / 128, 9), 256, 0, stream>>>(
        h, wq, qkv_b, qbuf, nullptr, kbuf, vbuf, 576);
    // 2. neighborhood attention -> attn_b (bf16)
    attn_kernel3<<<dim3(256, NHD), 256, 0, stream>>>(qbuf, kbuf, vbuf, rpb, attn_b);
    // 3. proj + residual + LN2 (fused, single-shot): out = x + |g1|*(attn@wp^T+b), h = LN2(out)
    proj_ln<<<NPIX / 64, 256, 0, stream>>>(
        attn_b, wp, proj_b, out, h, x, gamma1, quality, ln2_w, ln2_b);
    // 4. FC1 + GELU (single-K-shot 128x64) -> m1 (bf16)
    gemm_k192<1><<<dim3(NPIX / 128, 12), 256, 0, stream>>>(
        h, wf1, fc1_b, nullptr, m1, nullptr, nullptr, HID);
    // 5. FC2 + residual (64x64, BK=192): out += |g2|*(m1@wf2^T+b)
    fc2_gemm<<<dim3(NPIX / 64, 3), 256, 0, stream>>>(
        m1, wf2, fc2_b, out, out, gamma2, quality);
}